// Round 7
// baseline (948.032 us; speedup 1.0000x reference)
//
#include <hip/hip_runtime.h>
#include <hip/hip_bf16.h>
#include <cstdint>
#include <cstddef>

// Problem constants
constexpr int T = 8;
constexpr int C = 256;     // feature channels = GEMM K
constexpr int N = 4096;    // H*W pixels per frame
constexpr float TEMP_INV = 14.285714285714286f;  // 1/0.07
constexpr float EPS = 1e-8f;

typedef __bf16 bf16;
typedef __bf16 bf16x8 __attribute__((ext_vector_type(8)));
typedef float floatx4 __attribute__((ext_vector_type(4)));

// ---------------------------------------------------------------------------
// Per-frame dice deviation -> use_curr flag; zero counters.
__global__ void uflag_kernel(const float* __restrict__ cur,
                             const float* __restrict__ hist,
                             float* __restrict__ uflag,
                             int* __restrict__ nfg, int* __restrict__ nbg,
                             int* __restrict__ donecnt) {
    int t = blockIdx.x;
    int tid = threadIdx.x;
    int lane = tid & 63;
    int w = tid >> 6;
    float s1 = 0.f, sc = 0.f, sh = 0.f;
    #pragma unroll
    for (int it = 0; it < 4; ++it) {
        int p = it * 1024 + tid;
        float c = cur[t * N + p];
        float h = hist[t * N + p];
        float cb = c > 0.5f ? 1.f : 0.f;
        float hb = h > 0.5f ? 1.f : 0.f;
        s1 += cb * hb; sc += cb; sh += hb;
    }
    for (int o = 32; o > 0; o >>= 1) {
        s1 += __shfl_down(s1, o);
        sc += __shfl_down(sc, o);
        sh += __shfl_down(sh, o);
    }
    __shared__ float r1[16], r2[16], r3[16];
    if (lane == 0) { r1[w] = s1; r2[w] = sc; r3[w] = sh; }
    __syncthreads();
    if (tid == 0) {
        float e1 = 0.f, scs = 0.f, shs = 0.f;
        for (int i = 0; i < 16; ++i) { e1 += r1[i]; scs += r2[i]; shs += r3[i]; }
        float e2 = scs + shs;
        float m1 = (2.f * e1 + EPS) / (e2 + EPS);
        float m2 = (e1 + EPS) / (e2 - e1 + EPS);
        float dev = 1.f - 0.5f * (m1 + m2);
        uflag[t] = (dev <= 0.0f) ? 1.f : 0.f;
        nfg[t] = 0;
        nbg[t] = 0;
        if (t == 0) donecnt[0] = 0;
    }
}

// ---------------------------------------------------------------------------
// Normalize + labels + rank-compaction + swizzled scatter, all in one pass.
// Block = 64 pixels of one frame. fg pixel rank r -> fpack row r; bg pixel
// rank r -> fpack row 4095-r (fg+bg = 4096 rows exactly; every row written).
__global__ __launch_bounds__(256, 4) void normalize_kernel(const float* __restrict__ feat,
                                                           const float* __restrict__ cur,
                                                           const float* __restrict__ hist,
                                                           const float* __restrict__ uflag,
                                                           float* __restrict__ out_labels,
                                                           float* __restrict__ negbuf,
                                                           float* __restrict__ posc,
                                                           bf16* __restrict__ fpack,
                                                           int* __restrict__ nfg,
                                                           int* __restrict__ nbg) {
    __shared__ bf16 tile[64 * 258];    // [n][c] true chunk order, pad 258
    __shared__ float partial[256];
    __shared__ float rnorm_s[64];
    __shared__ int rowpk_s[64];
    int t = blockIdx.x >> 6;
    int n0 = (blockIdx.x & 63) * 64;
    int tid = threadIdx.x;
    int lane63 = tid & 63;
    int w = tid >> 6;
    const float* fb = feat + (size_t)t * C * N;
    float ss = 0.f;
    #pragma unroll 16
    for (int it = 0; it < 64; ++it) {
        int c = w * 64 + it;
        float v = fb[(size_t)c * N + n0 + lane63];
        ss += v * v;
        tile[lane63 * 258 + c] = (bf16)v;
    }
    partial[tid] = ss;
    __syncthreads();
    if (tid < 64) {                    // wave 0 only
        float s = partial[tid] + partial[tid + 64] + partial[tid + 128] + partial[tid + 192];
        float r = 1.f / fmaxf(sqrtf(s), 1e-12f);
        rnorm_s[tid] = r;
        int gi = t * N + n0 + tid;
        float lab = (uflag[t] != 0.f) ? cur[gi] : hist[gi];
        out_labels[gi] = lab;
        bool fg = lab > 0.5f;
        unsigned long long b = __ballot(fg);
        unsigned long long lowmask = (tid == 63) ? 0x7fffffffffffffffull
                                                 : ((1ull << tid) - 1ull);
        int rank_fg = __popcll(b & lowmask);
        int rank_bg = __popcll((~b) & lowmask);
        int cnt = __popcll(b);
        int base_fg = 0, base_bg = 0;
        if (tid == 0) {
            base_fg = atomicAdd(&nfg[t], cnt);
            base_bg = atomicAdd(&nbg[t], 64 - cnt);
        }
        base_fg = __shfl(base_fg, 0);
        base_bg = __shfl(base_bg, 0);
        int rank = fg ? (base_fg + rank_fg) : (base_bg + rank_bg);
        int rowpk = fg ? rank : (4095 - rank);
        rowpk_s[tid] = rowpk;
        if (fg) {
            posc[t * N + rank] = s * r * r;
            negbuf[t * N + rank] = 0.f;
        }
    }
    __syncthreads();
    bf16* fp = fpack + (size_t)t * N * C;
    #pragma unroll
    for (int it = 0; it < 8; ++it) {
        int l = it * 256 + tid;        // 16B-chunk index within tile, 0..2047
        int n = l >> 5;                // tile pixel
        int c8 = l & 31;               // true chunk 0..31
        int rp = rowpk_s[n];
        int slot = (c8 & ~7) | ((c8 & 7) ^ (rp & 7));   // XOR-swizzled store pos
        float r = rnorm_s[n];
        bf16x8 vin = *(const bf16x8*)&tile[n * 258 + c8 * 8];
        bf16x8 vo;
        for (int j = 0; j < 8; ++j) vo[j] = (bf16)((float)vin[j] * r);
        *(bf16x8*)(fp + (size_t)rp * C + slot * 8) = vo;
    }
}

// ---------------------------------------------------------------------------
// sim GEMM + exp + bg row-sum, AITER-style K-loop:
//   global_load (per-lane dwordx4, issued one K-step ahead) -> VGPR ->
//   ds_write into double-buffered LDS, ONE barrier per K-step.
// The vmcnt drain at each barrier targets loads aged by a full compute phase.
// Loss fused via completion counter (last block computes the scalar loss).
__global__ __launch_bounds__(256, 2) void sim_kernel(const bf16* __restrict__ fpack,
                                                     const int* __restrict__ nfg,
                                                     const int* __restrict__ nbg,
                                                     float* __restrict__ neg,
                                                     const float* __restrict__ posc,
                                                     int* __restrict__ donecnt,
                                                     float* __restrict__ out_loss) {
    __shared__ bf16 lds[2][2][128 * 64];   // [buf][A/B][rows x 64ch], 64 KB
    __shared__ float red[256];
    __shared__ int last_s;

    int tid = threadIdx.x;
    int t = blockIdx.x & 7;            // frame -> XCD pin
    int tile = blockIdx.x >> 3;
    int rowbase = (tile >> 5) * 128;
    int colbase = (tile & 31) * 128;
    int nfgt = nfg[t];
    int nbgt = nbg[t];

    if (rowbase < nfgt && colbase < nbgt) {     // block-uniform
        int lane = tid & 63;
        int w = tid >> 6;
        int quad = lane >> 4;
        const char* fb = (const char*)(fpack + (size_t)t * N * C);

        // staging address precompute: thread stages 4 A-chunks + 4 B-chunks/K-step
        int aoff[4], boff[4], aldso[4], bldso[4];
        #pragma unroll
        for (int s = 0; s < 4; ++s) {
            int c = s * 256 + tid;             // chunk 0..1023
            int rl = c >> 3;                   // local row 0..127
            int sub = c & 7;                   // true K-sub within step
            int pa = sub ^ (rl & 7);           // fpack/LDS swizzled slot (A)
            aoff[s]  = (rowbase + rl) * 512 + pa * 16;
            aldso[s] = rl * 128 + pa * 16;
            int gbrow = 4095 - (colbase + rl); // bg rank -> fpack row
            int pb = sub ^ (gbrow & 7);
            boff[s]  = gbrow * 512 + pb * 16;
            bldso[s] = rl * 128 + pb * 16;
        }

        float4 aR[4], bR[4];
        floatx4 acc[4][4];
        #pragma unroll
        for (int i = 0; i < 4; ++i)
            #pragma unroll
            for (int j = 0; j < 4; ++j)
                acc[i][j] = (floatx4){0.f, 0.f, 0.f, 0.f};

        int r0w = (w & 1) * 64;
        int c0w = (w >> 1) * 64;

        // prologue: load(0), write buf0, load(1)
        #pragma unroll
        for (int s = 0; s < 4; ++s) {
            aR[s] = *(const float4*)(fb + aoff[s]);
            bR[s] = *(const float4*)(fb + boff[s]);
        }
        #pragma unroll
        for (int s = 0; s < 4; ++s) {
            *(float4*)((char*)&lds[0][0][0] + aldso[s]) = aR[s];
            *(float4*)((char*)&lds[0][1][0] + bldso[s]) = bR[s];
        }
        #pragma unroll
        for (int s = 0; s < 4; ++s) {
            aR[s] = *(const float4*)(fb + aoff[s] + 128);
            bR[s] = *(const float4*)(fb + boff[s] + 128);
        }
        __syncthreads();

        #pragma unroll
        for (int ks = 0; ks < 4; ++ks) {
            if (ks < 3) {
                // write loads(ks+1) into the other buffer (readers done at prev barrier)
                int nb = (ks + 1) & 1;
                #pragma unroll
                for (int s = 0; s < 4; ++s) {
                    *(float4*)((char*)&lds[nb][0][0] + aldso[s]) = aR[s];
                    *(float4*)((char*)&lds[nb][1][0] + bldso[s]) = bR[s];
                }
                if (ks < 2) {   // issue loads(ks+2); they age through compute(ks)
                    #pragma unroll
                    for (int s = 0; s < 4; ++s) {
                        aR[s] = *(const float4*)(fb + aoff[s] + (ks + 2) * 128);
                        bR[s] = *(const float4*)(fb + boff[s] + (ks + 2) * 128);
                    }
                }
            }
            const char* la = (const char*)&lds[ks & 1][0][0];
            const char* lb = (const char*)&lds[ks & 1][1][0];
            #pragma unroll
            for (int kk = 0; kk < 2; ++kk) {
                int subt = kk * 4 + quad;          // true chunk wanted (0..7)
                bf16x8 af[4], bfr[4];
                #pragma unroll
                for (int i = 0; i < 4; ++i) {
                    int r = r0w + 16 * i + (lane & 15);
                    int st = subt ^ (r & 7);
                    af[i] = *(const bf16x8*)(la + r * 128 + st * 16);
                }
                #pragma unroll
                for (int j = 0; j < 4; ++j) {
                    int cl = c0w + 16 * j + (lane & 15);
                    int st = subt ^ 7 ^ (cl & 7);  // bg rows stored descending
                    bfr[j] = *(const bf16x8*)(lb + cl * 128 + st * 16);
                }
                #pragma unroll
                for (int i = 0; i < 4; ++i)
                    #pragma unroll
                    for (int j = 0; j < 4; ++j)
                        acc[i][j] = __builtin_amdgcn_mfma_f32_16x16x32_bf16(af[i], bfr[j], acc[i][j], 0, 0, 0);
            }
            __syncthreads();
        }

        // epilogue: exp + col-mask (select, inf-safe) + row reduce + atomics
        bool okc[4];
        #pragma unroll
        for (int j = 0; j < 4; ++j)
            okc[j] = (colbase + c0w + 16 * j + (lane & 15)) < nbgt;
        #pragma unroll
        for (int i = 0; i < 4; ++i) {
            #pragma unroll
            for (int reg = 0; reg < 4; ++reg) {
                float msum = 0.f;
                #pragma unroll
                for (int j = 0; j < 4; ++j) {
                    float e = __expf(acc[i][j][reg] * TEMP_INV);
                    msum += okc[j] ? e : 0.f;
                }
                msum += __shfl_xor(msum, 1);
                msum += __shfl_xor(msum, 2);
                msum += __shfl_xor(msum, 4);
                msum += __shfl_xor(msum, 8);
                if ((lane & 15) == 0) {
                    int row = rowbase + r0w + 16 * i + quad * 4 + reg;
                    if (row < nfgt) atomicAdd(&neg[t * N + row], msum);
                }
            }
        }
    }

    // completion handshake; last block computes the final loss scalar
    __syncthreads();
    __threadfence();
    if (tid == 0) last_s = (atomicAdd(donecnt, 1) == (int)gridDim.x - 1) ? 1 : 0;
    __syncthreads();
    if (last_s) {
        __threadfence();
        float fsum = 0.f, vsum = 0.f;   // only tid 0's copy is used
        for (int tt = 0; tt < T; ++tt) {
            int nf = nfg[tt];
            float s = 0.f;
            for (int k = tid; k < nf; k += 256) {
                float pos = __expf(posc[tt * N + k] * TEMP_INV);
                s += logf((pos + neg[tt * N + k] + EPS) / pos);
            }
            red[tid] = s;
            __syncthreads();
            for (int o = 128; o > 0; o >>= 1) {
                if (tid < o) red[tid] += red[tid + o];
                __syncthreads();
            }
            if (tid == 0) {
                float valid = (nf > 0 && nbg[tt] > 0) ? 1.f : 0.f;
                fsum += valid * (red[0] / fmaxf((float)nf, 1.f));
                vsum += valid;
            }
            __syncthreads();
        }
        if (tid == 0)
            out_loss[0] = (vsum > 0.f) ? fsum / fmaxf(vsum, 1.f) : 0.f;
    }
}

// ---------------------------------------------------------------------------
extern "C" void kernel_launch(void* const* d_in, const int* in_sizes, int n_in,
                              void* d_out, int out_size, void* d_ws, size_t ws_size,
                              hipStream_t stream) {
    const float* cur  = (const float*)d_in[0];
    const float* hist = (const float*)d_in[1];
    const float* feat = (const float*)d_in[2];
    float* out = (float*)d_out;   // labels[32768] ++ loss[1]

    char* ws = (char*)d_ws;
    bf16*  fpack   = (bf16*)ws;                           // 8*4096*256 bf16 = 16 MiB
    size_t off = (size_t)T * N * C * sizeof(bf16);
    float* negbuf  = (float*)(ws + off);  off += (size_t)T * N * 4;
    float* posc    = (float*)(ws + off);  off += (size_t)T * N * 4;
    float* uflag   = (float*)(ws + off);  off += 64;
    int*   nfg     = (int*)(ws + off);
    int*   nbg     = nfg + 8;
    int*   donecnt = nbg + 8;

    uflag_kernel<<<8, 1024, 0, stream>>>(cur, hist, uflag, nfg, nbg, donecnt);
    normalize_kernel<<<512, 256, 0, stream>>>(feat, cur, hist, uflag, out, negbuf, posc, fpack, nfg, nbg);
    sim_kernel<<<8192, 256, 0, stream>>>(fpack, nfg, nbg, negbuf, posc, donecnt, out + 32768);
}

// Round 8
// 250.236 us; speedup vs baseline: 3.7886x; 3.7886x over previous
//
#include <hip/hip_runtime.h>
#include <hip/hip_bf16.h>
#include <cstdint>
#include <cstddef>

// Problem constants
constexpr int T = 8;
constexpr int C = 256;     // feature channels = GEMM K
constexpr int N = 4096;    // H*W pixels per frame
constexpr float TEMP_INV = 14.285714285714286f;  // 1/0.07
constexpr float EPS = 1e-8f;

typedef __bf16 bf16;
typedef __bf16 bf16x8 __attribute__((ext_vector_type(8)));
typedef float floatx4 __attribute__((ext_vector_type(4)));

// ---------------------------------------------------------------------------
// async global->LDS, 16B per lane, wave-uniform LDS base + lane*16
__device__ __forceinline__ void async_copy16(const bf16* g, bf16* l) {
    __builtin_amdgcn_global_load_lds((const __attribute__((address_space(1))) void*)g,
                                     (__attribute__((address_space(3))) void*)l,
                                     16, 0, 0);
}

// ---------------------------------------------------------------------------
// Per-frame dice deviation -> use_curr flag; zero counters/queues.
__global__ void uflag_kernel(const float* __restrict__ cur,
                             const float* __restrict__ hist,
                             float* __restrict__ uflag,
                             int* __restrict__ nfg, int* __restrict__ nbg,
                             int* __restrict__ qcnt, int* __restrict__ donecnt) {
    int t = blockIdx.x;
    int tid = threadIdx.x;
    int lane = tid & 63;
    int w = tid >> 6;
    float s1 = 0.f, sc = 0.f, sh = 0.f;
    #pragma unroll
    for (int it = 0; it < 4; ++it) {
        int p = it * 1024 + tid;
        float c = cur[t * N + p];
        float h = hist[t * N + p];
        float cb = c > 0.5f ? 1.f : 0.f;
        float hb = h > 0.5f ? 1.f : 0.f;
        s1 += cb * hb; sc += cb; sh += hb;
    }
    for (int o = 32; o > 0; o >>= 1) {
        s1 += __shfl_down(s1, o);
        sc += __shfl_down(sc, o);
        sh += __shfl_down(sh, o);
    }
    __shared__ float r1[16], r2[16], r3[16];
    if (lane == 0) { r1[w] = s1; r2[w] = sc; r3[w] = sh; }
    __syncthreads();
    if (tid == 0) {
        float e1 = 0.f, scs = 0.f, shs = 0.f;
        for (int i = 0; i < 16; ++i) { e1 += r1[i]; scs += r2[i]; shs += r3[i]; }
        float e2 = scs + shs;
        float m1 = (2.f * e1 + EPS) / (e2 + EPS);
        float m2 = (e1 + EPS) / (e2 - e1 + EPS);
        float dev = 1.f - 0.5f * (m1 + m2);
        uflag[t] = (dev <= 0.0f) ? 1.f : 0.f;
        nfg[t] = 0;
        nbg[t] = 0;
        qcnt[t] = 0;
        if (t == 0) donecnt[0] = 0;
    }
}

// ---------------------------------------------------------------------------
// Normalize + labels + rank-compaction + swizzled scatter, all in one pass.
// fg pixel rank r -> fpack row r; bg pixel rank r -> fpack row 4095-r.
__global__ __launch_bounds__(256, 4) void normalize_kernel(const float* __restrict__ feat,
                                                           const float* __restrict__ cur,
                                                           const float* __restrict__ hist,
                                                           const float* __restrict__ uflag,
                                                           float* __restrict__ out_labels,
                                                           float* __restrict__ negbuf,
                                                           float* __restrict__ posc,
                                                           bf16* __restrict__ fpack,
                                                           int* __restrict__ nfg,
                                                           int* __restrict__ nbg) {
    __shared__ bf16 tile[64 * 258];    // [n][c] true chunk order, pad 258
    __shared__ float partial[256];
    __shared__ float rnorm_s[64];
    __shared__ int rowpk_s[64];
    int t = blockIdx.x >> 6;
    int n0 = (blockIdx.x & 63) * 64;
    int tid = threadIdx.x;
    int lane63 = tid & 63;
    int w = tid >> 6;
    const float* fb = feat + (size_t)t * C * N;
    float ss = 0.f;
    #pragma unroll 16
    for (int it = 0; it < 64; ++it) {
        int c = w * 64 + it;
        float v = fb[(size_t)c * N + n0 + lane63];
        ss += v * v;
        tile[lane63 * 258 + c] = (bf16)v;
    }
    partial[tid] = ss;
    __syncthreads();
    if (tid < 64) {                    // wave 0 only
        float s = partial[tid] + partial[tid + 64] + partial[tid + 128] + partial[tid + 192];
        float r = 1.f / fmaxf(sqrtf(s), 1e-12f);
        rnorm_s[tid] = r;
        int gi = t * N + n0 + tid;
        float lab = (uflag[t] != 0.f) ? cur[gi] : hist[gi];
        out_labels[gi] = lab;
        bool fg = lab > 0.5f;
        unsigned long long b = __ballot(fg);
        unsigned long long lowmask = (tid == 63) ? 0x7fffffffffffffffull
                                                 : ((1ull << tid) - 1ull);
        int rank_fg = __popcll(b & lowmask);
        int rank_bg = __popcll((~b) & lowmask);
        int cnt = __popcll(b);
        int base_fg = 0, base_bg = 0;
        if (tid == 0) {
            base_fg = atomicAdd(&nfg[t], cnt);
            base_bg = atomicAdd(&nbg[t], 64 - cnt);
        }
        base_fg = __shfl(base_fg, 0);
        base_bg = __shfl(base_bg, 0);
        int rank = fg ? (base_fg + rank_fg) : (base_bg + rank_bg);
        int rowpk = fg ? rank : (4095 - rank);
        rowpk_s[tid] = rowpk;
        if (fg) {
            posc[t * N + rank] = s * r * r;
            negbuf[t * N + rank] = 0.f;
        }
    }
    __syncthreads();
    bf16* fp = fpack + (size_t)t * N * C;
    #pragma unroll
    for (int it = 0; it < 8; ++it) {
        int l = it * 256 + tid;        // 16B-chunk index within tile, 0..2047
        int n = l >> 5;                // tile pixel
        int c8 = l & 31;               // true chunk 0..31
        int rp = rowpk_s[n];
        int slot = (c8 & ~7) | ((c8 & 7) ^ (rp & 7));   // XOR-swizzled store pos
        float r = rnorm_s[n];
        bf16x8 vin = *(const bf16x8*)&tile[n * 258 + c8 * 8];
        bf16x8 vo;
        for (int j = 0; j < 8; ++j) vo[j] = (bf16)((float)vin[j] * r);
        *(bf16x8*)(fp + (size_t)rp * C + slot * 8) = vo;
    }
}

// ---------------------------------------------------------------------------
// sim GEMM + exp + bg row-sum. R6's proven inner loop (global_load_lds w16,
// XOR swizzle, 2 barriers/K-step) with PERSISTENT blocks + per-frame dynamic
// work queue over EXACTLY the active tiles; fused loss tail via completion
// counter (atomic reads keep visibility inside the coherent atomic domain).
__global__ __launch_bounds__(256, 4) void sim_kernel(const bf16* __restrict__ fpack,
                                                     const int* __restrict__ nfg,
                                                     const int* __restrict__ nbg,
                                                     float* __restrict__ neg,
                                                     const float* __restrict__ posc,
                                                     int* __restrict__ qcnt,
                                                     int* __restrict__ donecnt,
                                                     float* __restrict__ out_loss) {
    __shared__ bf16 a_lds[128 * 64];
    __shared__ bf16 b_lds[128 * 64];
    __shared__ int vt_s;
    __shared__ float red[256];
    __shared__ int last_s;

    int tid = threadIdx.x;
    int t = blockIdx.x & 7;            // frame -> XCD-pin heuristic (perf only)
    int nfgt = nfg[t];
    int nbgt = nbg[t];
    int nct = (nbgt + 127) >> 7;
    int ntiles = ((nfgt + 127) >> 7) * nct;   // exactly the active tiles
    int lane = tid & 63;
    int w = tid >> 6;
    int lrow = lane >> 3;
    int lchunk = lane & 7;
    int r0w = (w & 1) * 64;
    int c0w = (w >> 1) * 64;
    int quad = lane >> 4;
    const bf16* fb = fpack + (size_t)t * N * C;

    while (true) {
        __syncthreads();
        if (tid == 0) vt_s = atomicAdd(&qcnt[t], 1);
        __syncthreads();
        int vt = vt_s;
        if (vt >= ntiles) break;       // block-uniform
        int rowbase = (vt / nct) * 128;
        int colbase = (vt % nct) * 128;

        floatx4 acc[4][4];
        #pragma unroll
        for (int i = 0; i < 4; ++i)
            #pragma unroll
            for (int j = 0; j < 4; ++j)
                acc[i][j] = (floatx4){0.f, 0.f, 0.f, 0.f};

        for (int ks = 0; ks < 4; ++ks) {
            int k0 = ks * 64;
            __syncthreads();
            for (int s = 0; s < 4; ++s) {
                int q = w * 4 + s;                       // 0..15
                int ra = rowbase + q * 8 + lrow;         // fg rank (ascending)
                int rb = 4095 - (colbase + q * 8 + lrow);// bg rank (descending rows)
                async_copy16(fb + (size_t)ra * C + k0 + lchunk * 8, &a_lds[q * 512]);
                async_copy16(fb + (size_t)rb * C + k0 + lchunk * 8, &b_lds[q * 512]);
            }
            __syncthreads();
            for (int kk = 0; kk < 64; kk += 32) {
                int chread = (kk >> 3) + quad;           // true sub-chunk wanted
                bf16x8 af[4], bfr[4];
                #pragma unroll
                for (int i = 0; i < 4; ++i) {
                    int r = r0w + 16 * i + (lane & 15);
                    int chs = chread ^ (r & 7);
                    af[i] = *(const bf16x8*)&a_lds[r * 64 + chs * 8];
                }
                #pragma unroll
                for (int j = 0; j < 4; ++j) {
                    int cl = c0w + 16 * j + (lane & 15);
                    int chs = chread ^ 7 ^ (cl & 7);     // bg stored descending
                    bfr[j] = *(const bf16x8*)&b_lds[cl * 64 + chs * 8];
                }
                #pragma unroll
                for (int i = 0; i < 4; ++i)
                    #pragma unroll
                    for (int j = 0; j < 4; ++j)
                        acc[i][j] = __builtin_amdgcn_mfma_f32_16x16x32_bf16(af[i], bfr[j], acc[i][j], 0, 0, 0);
            }
        }

        // epilogue: exp + col-mask + row reduce + atomics
        bool okc[4];
        #pragma unroll
        for (int j = 0; j < 4; ++j)
            okc[j] = (colbase + c0w + 16 * j + (lane & 15)) < nbgt;
        #pragma unroll
        for (int i = 0; i < 4; ++i) {
            #pragma unroll
            for (int reg = 0; reg < 4; ++reg) {
                float msum = 0.f;
                #pragma unroll
                for (int j = 0; j < 4; ++j) {
                    float e = __expf(acc[i][j][reg] * TEMP_INV);
                    msum += okc[j] ? e : 0.f;
                }
                msum += __shfl_xor(msum, 1);
                msum += __shfl_xor(msum, 2);
                msum += __shfl_xor(msum, 4);
                msum += __shfl_xor(msum, 8);
                if ((lane & 15) == 0) {
                    int row = rowbase + r0w + 16 * i + quad * 4 + reg;
                    if (row < nfgt) atomicAdd(&neg[t * N + row], msum);
                }
            }
        }
    }

    // completion handshake; last block computes the final loss scalar
    __syncthreads();
    __threadfence();                   // release our neg atomics
    if (tid == 0) last_s = (atomicAdd(donecnt, 1) == (int)gridDim.x - 1) ? 1 : 0;
    __syncthreads();
    if (last_s) {
        float fsum = 0.f, vsum = 0.f;  // meaningful on tid 0 only
        for (int tt = 0; tt < T; ++tt) {
            int nf = nfg[tt];
            float s = 0.f;
            for (int k = tid; k < nf; k += 256) {
                float pos = __expf(posc[tt * N + k] * TEMP_INV);
                float ng = atomicAdd(&neg[tt * N + k], 0.f);   // coherent read
                s += logf((pos + ng + EPS) / pos);
            }
            red[tid] = s;
            __syncthreads();
            for (int o = 128; o > 0; o >>= 1) {
                if (tid < o) red[tid] += red[tid + o];
                __syncthreads();
            }
            if (tid == 0) {
                float valid = (nf > 0 && nbg[tt] > 0) ? 1.f : 0.f;
                fsum += valid * (red[0] / fmaxf((float)nf, 1.f));
                vsum += valid;
            }
            __syncthreads();
        }
        if (tid == 0)
            out_loss[0] = (vsum > 0.f) ? fsum / fmaxf(vsum, 1.f) : 0.f;
    }
}

// ---------------------------------------------------------------------------
extern "C" void kernel_launch(void* const* d_in, const int* in_sizes, int n_in,
                              void* d_out, int out_size, void* d_ws, size_t ws_size,
                              hipStream_t stream) {
    const float* cur  = (const float*)d_in[0];
    const float* hist = (const float*)d_in[1];
    const float* feat = (const float*)d_in[2];
    float* out = (float*)d_out;   // labels[32768] ++ loss[1]

    char* ws = (char*)d_ws;
    bf16*  fpack   = (bf16*)ws;                           // 8*4096*256 bf16 = 16 MiB
    size_t off = (size_t)T * N * C * sizeof(bf16);
    float* negbuf  = (float*)(ws + off);  off += (size_t)T * N * 4;
    float* posc    = (float*)(ws + off);  off += (size_t)T * N * 4;
    float* uflag   = (float*)(ws + off);  off += 64;
    int*   nfg     = (int*)(ws + off);
    int*   nbg     = nfg + 8;
    int*   qcnt    = nbg + 8;
    int*   donecnt = qcnt + 8;

    uflag_kernel<<<8, 1024, 0, stream>>>(cur, hist, uflag, nfg, nbg, qcnt, donecnt);
    normalize_kernel<<<512, 256, 0, stream>>>(feat, cur, hist, uflag, out, negbuf, posc, fpack, nfg, nbg);
    sim_kernel<<<1024, 256, 0, stream>>>(fpack, nfg, nbg, negbuf, posc, qcnt, donecnt, out + 32768);
}